// Round 3
// baseline (310.399 us; speedup 1.0000x reference)
//
#include <hip/hip_runtime.h>
#include <hip/hip_cooperative_groups.h>

namespace cg = cooperative_groups;

// Problem constants (from reference)
#define N_CAM   6
#define N_REF   4
#define N_HEADS 8
#define EMBD    256
#define HS      32
#define L       100     // seq_len = 10*10
#define BS      2
#define CAM_STRIDE (L * EMBD)   // 25600 floats per (b, cam)
#define CK      (N_CAM * L)     // 600 combined (cam, sk) index

// Workspace layout (floats):
//   wsum : 1536*256            = 393216
//   ktr  : 2*8*32*600          = 307200   [b][h][d][cam*100+sk]
//   P    : 12*200*256          = 614400   GEMM split-K partials [chunk][row][e]
//   vsum : 200*256             = 51200
//   E    : 2*100*8*100         = 160000   [b][sq][h][sk]
#define WS_WSUM 0
#define WS_KTR  (WS_WSUM + 1536*256)
#define WS_P    (WS_KTR + 307200)
#define WS_VSUM (WS_P + 12*200*256)
#define WS_E    (WS_VSUM + 51200)

#define NBLK 600

// ---------------------------------------------------------------------------
// One cooperative kernel, 600 blocks x 256 threads, 4 stages / 3 grid syncs:
//  S1: blocks [0,96)  : transpose feat -> ktr[b][h][d][cam*100+sk]
//      blocks [96,600): fold W_v (1536x1024) over 4 ref slots -> wsum (1536x256)
//  S2: all 600 blocks : split-K GEMM partials P (M=200,N=256,K=1536; 12 chunks)
//  S3: blocks [0,200) : reduce P -> vsum (+ folded bias)
//      blocks [200,600): E[b][sq][h][sk] = sum_cam exp(q.k * scale)
//  S4: blocks [0,200) : out = (E @ vsum) / (4 * sumE)
// ---------------------------------------------------------------------------
__global__ __launch_bounds__(256, 4) void fused_kernel(const float* __restrict__ feat,
                                                       const float* __restrict__ query,
                                                       const float4* __restrict__ Wv4,
                                                       const float* __restrict__ b_v,
                                                       float* __restrict__ ws,
                                                       float* __restrict__ out) {
    cg::grid_group grid = cg::this_grid();
    __shared__ float smem[100 * 33];     // 13.2 KB, reused per stage
    const int t   = threadIdx.x;
    const int blk = blockIdx.x;

    // ===================== S1: transpose + W fold =====================
    if (blk < 96) {
        // one block per (b, cam, h); smem as tile[100][33] (+1 pad)
        int b   = blk / 48;
        int rem = blk - b * 48;
        int cam = rem >> 3;
        int h   = rem & 7;
        const float* src = feat + (size_t)(b * N_CAM + cam) * CAM_STRIDE + h * HS;
        for (int idx = t; idx < 100 * 32; idx += 256) {
            int sk = idx >> 5;
            int d  = idx & 31;
            smem[sk * 33 + d] = src[sk * EMBD + d];      // 128B-contiguous runs
        }
        __syncthreads();
        float* ktr = ws + WS_KTR;
        for (int idx = t; idx < 100 * 32; idx += 256) {
            int d  = idx / 100;
            int sk = idx - d * 100;
            ktr[((size_t)(b * N_HEADS + h) * HS + d) * CK + cam * L + sk] = smem[sk * 33 + d];
        }
    } else {
        // wsum[i][e] = sum_ref W_v[i][ref*256+e]; 1536*64 float4 outputs
        int tid = (blk - 96) * 256 + t;                  // 504*256 = 129024 threads
        if (tid < 1536 * 64) {
            int i  = tid >> 6;
            int e4 = tid & 63;
            const float4* row = Wv4 + (size_t)i * 256;
            float4 a = row[e4];
            float4 b = row[64 + e4];
            float4 c = row[128 + e4];
            float4 d = row[192 + e4];
            float4 o;
            o.x = a.x + b.x + c.x + d.x;
            o.y = a.y + b.y + c.y + d.y;
            o.z = a.z + b.z + c.z + d.z;
            o.w = a.w + b.w + c.w + d.w;
            ((float4*)(ws + WS_WSUM))[(size_t)i * 64 + e4] = o;
        }
    }
    grid.sync();

    // ===================== S2: split-K GEMM partials =====================
    {
        // block = (rg, c): rows rg*4..+4, K-chunk c (128 of 1536)
        const int rg = blk / 12;
        const int c  = blk - rg * 12;
        const int r0 = rg * 4;
        const int k0 = c * 128;
        const int cam    = c >> 1;        // 128-chunks never cross a camera
        const int e2base = (c & 1) << 7;

        float* a_tile = smem;             // [4][128]
        for (int idx = t; idx < 4 * 128; idx += 256) {
            int j  = idx >> 7;
            int kk = idx & 127;
            int row = r0 + j;
            int b = row >= 100;
            int s = row - b * 100;
            a_tile[j * 128 + kk] =
                feat[(size_t)(b * N_CAM + cam) * CAM_STRIDE + s * EMBD + e2base + kk];
        }
        __syncthreads();

        float acc[4] = {0.f, 0.f, 0.f, 0.f};
        const float* wp = ws + WS_WSUM + (size_t)k0 * 256 + t;
#pragma unroll 8
        for (int kk = 0; kk < 128; ++kk) {
            float w = wp[kk * 256];       // coalesced across t
#pragma unroll
            for (int j = 0; j < 4; ++j) acc[j] += a_tile[j * 128 + kk] * w;
        }

        float* P = ws + WS_P;
#pragma unroll
        for (int j = 0; j < 4; ++j)
            P[((size_t)c * 200 + r0 + j) * 256 + t] = acc[j];
    }
    grid.sync();

    // ===================== S3: reduce | E-compute =====================
    if (blk < 200) {
        const int row = blk;
        const float* P = ws + WS_P;
        float acc = b_v[t] + b_v[256 + t] + b_v[512 + t] + b_v[768 + t];
#pragma unroll
        for (int c = 0; c < 12; ++c)
            acc += P[((size_t)c * 200 + row) * 256 + t];
        ws[WS_VSUM + (size_t)row * 256 + t] = acc;
    } else {
        // block = (b, h, sq-tile of 4)
        float* q_s = smem;                // [4][32]
        float* es  = smem + 128;          // [4][600]
        int idx = blk - 200;              // [0,400)
        int b   = idx / 200;
        int rem = idx - b * 200;
        int h   = rem / 25;
        int sqt = rem - h * 25;
        int sq0 = sqt * 4;

        if (t < 128) {
            int sqj = t >> 5;
            int d   = t & 31;
            q_s[sqj * 32 + d] = query[(size_t)(b * L + sq0 + sqj) * EMBD + h * HS + d];
        }
        __syncthreads();

        const float scale = 0.17677669529663687f;  // 1/sqrt(32)
        const float* kt = ws + WS_KTR + (size_t)(b * N_HEADS + h) * HS * CK;

#pragma unroll
        for (int i = 0; i < 3; ++i) {
            int ck = t + i * 256;
            if (ck < CK) {
                float acc0 = 0.f, acc1 = 0.f, acc2 = 0.f, acc3 = 0.f;
#pragma unroll 8
                for (int d = 0; d < 32; ++d) {
                    float k = kt[(size_t)d * CK + ck];   // coalesced across lanes
                    acc0 += q_s[0 * 32 + d] * k;
                    acc1 += q_s[1 * 32 + d] * k;
                    acc2 += q_s[2 * 32 + d] * k;
                    acc3 += q_s[3 * 32 + d] * k;
                }
                es[0 * CK + ck] = __expf(acc0 * scale);
                es[1 * CK + ck] = __expf(acc1 * scale);
                es[2 * CK + ck] = __expf(acc2 * scale);
                es[3 * CK + ck] = __expf(acc3 * scale);
            }
        }
        __syncthreads();

        // fold cameras: E[sq][sk] = sum_cam es[sq][cam*100+sk]
        float* E = ws + WS_E;
        for (int p = t; p < 4 * L; p += 256) {
            int sqj = p / 100;
            int sk  = p - sqj * 100;
            float e = 0.f;
#pragma unroll
            for (int cam = 0; cam < N_CAM; ++cam)
                e += es[sqj * CK + cam * L + sk];
            E[((size_t)(b * L + sq0 + sqj) * N_HEADS + h) * L + sk] = e;
        }
    }
    grid.sync();

    // ===================== S4: output =====================
    if (blk < 200) {
        const int b  = blk / 100;
        const int sq = blk - b * 100;
        const int h  = t >> 5;

        const float* Eh = ws + WS_E + ((size_t)(b * L + sq) * N_HEADS + h) * L;
        const float* vb = ws + WS_VSUM + (size_t)b * L * EMBD + t;

        float acc = 0.f, sumE = 0.f;
#pragma unroll 4
        for (int sk = 0; sk < L; ++sk) {
            float e = Eh[sk];             // broadcast within 32-lane head group
            acc  += e * vb[sk * EMBD];    // coalesced
            sumE += e;
        }
        out[(size_t)(b * L + sq) * EMBD + t] = acc * (0.25f / sumE);
    }
}

// ---------------------------------------------------------------------------
extern "C" void kernel_launch(void* const* d_in, const int* in_sizes, int n_in,
                              void* d_out, int out_size, void* d_ws, size_t ws_size,
                              hipStream_t stream) {
    const float* feat  = (const float*)d_in[0];  // (2,1,6,256,10,10)
    const float* query = (const float*)d_in[1];  // (2,100,256)
    const float4* Wv   = (const float4*)d_in[2]; // (1536,1024)
    const float* bv    = (const float*)d_in[3];  // (1024,)
    float* outp = (float*)d_out;                 // (2,100,256)
    float* ws   = (float*)d_ws;

    void* args[] = {(void*)&feat, (void*)&query, (void*)&Wv,
                    (void*)&bv,   (void*)&ws,    (void*)&outp};
    hipLaunchCooperativeKernel((void*)fused_kernel, dim3(NBLK), dim3(256),
                               args, 0, stream);
}

// Round 4
// 115.722 us; speedup vs baseline: 2.6823x; 2.6823x over previous
//
#include <hip/hip_runtime.h>

// Problem constants (from reference)
#define N_CAM   6
#define N_HEADS 8
#define EMBD    256
#define HS      32
#define L       100     // seq_len = 10*10
#define BS      2
#define CAM_STRIDE (L * EMBD)   // 25600 floats per (b, cam)
#define CK      (N_CAM * L)     // 600 combined (cam, sk) index

// Workspace layout (floats):
//   wsum : 1536*256 = 393216   folded W (sum over 4 ref slots)
//   P    : 200*256*4 = 204800  split-K partials, float4 per (row,e): .c = chunk
//   E    : 200*8*100 = 160000  E[b*100+sq][h][sk] (camera-folded exp scores)
#define WS_WSUM 0
#define WS_P    (WS_WSUM + 1536 * 256)
#define WS_E    (WS_P + 200 * 256 * 4)

// ---------------------------------------------------------------------------
// K1 (784 blocks) — two INDEPENDENT jobs in one launch:
//  blocks [0,384):  wsum[i][e] = sum_ref W_v[i][ref*256+e]
//  blocks [384,784): E[b,sq,h,sk] = sum_cam exp(q.k/sqrt(32)), straight from
//                    feat via LDS tiles (no global transpose pass).
// ---------------------------------------------------------------------------
__global__ __launch_bounds__(256) void prep_kernel(const float* __restrict__ feat,
                                                   const float* __restrict__ query,
                                                   const float4* __restrict__ Wv4,
                                                   float* __restrict__ ws) {
    const int t = threadIdx.x;
    if (blockIdx.x < 384) {
        // ---- W fold: 384*256 threads = 1536 rows x 64 float4 cols ----
        int tid = blockIdx.x * 256 + t;
        int i  = tid >> 6;
        int e4 = tid & 63;
        const float4* row = Wv4 + (size_t)i * 256;
        float4 a = row[e4];
        float4 b = row[64 + e4];
        float4 c = row[128 + e4];
        float4 d = row[192 + e4];
        float4 o;
        o.x = a.x + b.x + c.x + d.x;
        o.y = a.y + b.y + c.y + d.y;
        o.z = a.z + b.z + c.z + d.z;
        o.w = a.w + b.w + c.w + d.w;
        ((float4*)(ws + WS_WSUM))[(size_t)i * 64 + e4] = o;
    } else {
        // ---- E-compute: block = (b, h, sq-tile of 4) ----
        __shared__ float q_s[4 * 32];
        __shared__ float ks[64 * 33];     // [ck_local][33] pad -> 2-way (free)
        __shared__ float es[4 * CK];      // exp(scores) 4 sq x 600 ck
        int idx = blockIdx.x - 384;       // [0,400)
        int b   = idx / 200;
        int rem = idx - b * 200;
        int h   = rem / 25;
        int sqt = rem - h * 25;
        int sq0 = sqt * 4;

        if (t < 128)
            q_s[t] = query[(size_t)(b * L + sq0 + (t >> 5)) * EMBD + h * HS + (t & 31)];

        const float scale = 0.17677669529663687f;   // 1/sqrt(32)
        const float* fb = feat + (size_t)b * N_CAM * CAM_STRIDE + h * HS;

        const int ckl = t & 63;
        const int sqj = t >> 6;
        for (int tile = 0; tile < 10; ++tile) {
            int ck0 = tile * 64;
            int n   = (ck0 + 64 <= CK) ? 64 : (CK - ck0);   // 64, last tile 24
            // stage K-tile: ks[ckl][d] = feat[b, cam, sk, h*32+d]
            for (int i = t; i < n * 32; i += 256) {
                int cl = i >> 5, d = i & 31;
                int ck = ck0 + cl;
                int cam = ck / 100, sk = ck - cam * 100;
                ks[cl * 33 + d] = fb[(size_t)cam * CAM_STRIDE + sk * EMBD + d];
            }
            __syncthreads();
            if (ckl < n) {
                float dot = 0.f;
#pragma unroll
                for (int d = 0; d < 32; ++d)
                    dot += q_s[sqj * 32 + d] * ks[ckl * 33 + d];   // q_s: broadcast
                es[sqj * CK + ck0 + ckl] = __expf(dot * scale);
            }
            __syncthreads();
        }

        // camera fold -> E
        float* E = ws + WS_E;
        for (int p = t; p < 4 * L; p += 256) {
            int sj = p / 100, sk = p - sj * 100;
            float e = 0.f;
#pragma unroll
            for (int cam = 0; cam < N_CAM; ++cam)
                e += es[sj * CK + cam * L + sk];
            E[((size_t)(b * L + sq0 + sj) * N_HEADS + h) * L + sk] = e;
        }
    }
}

// ---------------------------------------------------------------------------
// K2 (200 blocks): split-K GEMM partials. block = (rg, c): rows rg*4..+4,
// K-chunk c of 384 (4 chunks cover K=1536). Output packed float4 per (row,e)
// so K3 reduces chunks with one 16B load.
// ---------------------------------------------------------------------------
__global__ __launch_bounds__(256) void gemm_kernel(const float* __restrict__ feat,
                                                   const float* __restrict__ ws_r,
                                                   float* __restrict__ ws_w) {
    __shared__ float a_tile[384 * 4];     // [kk][j] -> broadcast reads
    const int t  = threadIdx.x;
    const int rg = blockIdx.x >> 2;
    const int c  = blockIdx.x & 3;
    const int r0 = rg * 4;
    const int k0 = c * 384;

    // stage A: a_tile[kk*4+j] = v_in[r0+j][k0+kk]
    for (int idx = t; idx < 1536; idx += 256) {
        int kk = idx >> 2, j = idx & 3;
        int k  = k0 + kk;
        int cam = k >> 8, e2 = k & 255;
        int row = r0 + j;
        int b = row >= 100;
        int s = row - b * 100;
        a_tile[idx] = feat[(size_t)(b * N_CAM + cam) * CAM_STRIDE + s * EMBD + e2];
    }
    __syncthreads();

    float acc0 = 0.f, acc1 = 0.f, acc2 = 0.f, acc3 = 0.f;
    const float* wp = ws_r + WS_WSUM + (size_t)k0 * 256 + t;
#pragma unroll 16
    for (int kk = 0; kk < 384; ++kk) {
        float w = wp[(size_t)kk * 256];   // coalesced across t
        acc0 += a_tile[kk * 4 + 0] * w;
        acc1 += a_tile[kk * 4 + 1] * w;
        acc2 += a_tile[kk * 4 + 2] * w;
        acc3 += a_tile[kk * 4 + 3] * w;
    }

    float* P = ws_w + WS_P;
    P[((size_t)(r0 + 0) * 256 + t) * 4 + c] = acc0;
    P[((size_t)(r0 + 1) * 256 + t) * 4 + c] = acc1;
    P[((size_t)(r0 + 2) * 256 + t) * 4 + c] = acc2;
    P[((size_t)(r0 + 3) * 256 + t) * 4 + c] = acc3;
}

// ---------------------------------------------------------------------------
// K3 (200 blocks): block = (b, sq).
// out[b,sq,e] = (sum_sk E[sq,h,sk]*(sum_c P + bias_e)) / (4*sumE)
//             = (sum_sk E*(p.x+p.y+p.z+p.w) + sumE*bias_e) * 0.25/sumE
// ---------------------------------------------------------------------------
__global__ __launch_bounds__(256) void out_kernel(const float* __restrict__ ws,
                                                  const float* __restrict__ b_v,
                                                  float* __restrict__ out) {
    __shared__ float E_s[N_HEADS * L];    // 800 floats
    const int t  = threadIdx.x;
    const int b  = blockIdx.x / 100;
    const int sq = blockIdx.x - b * 100;

    const float* E = ws + WS_E + (size_t)(b * L + sq) * N_HEADS * L;
    for (int i = t; i < N_HEADS * L; i += 256) E_s[i] = E[i];
    __syncthreads();

    const int h = t >> 5;
    float sumE = 0.f;
#pragma unroll 4
    for (int sk = 0; sk < L; ++sk) sumE += E_s[h * L + sk];   // broadcast reads

    float bias = b_v[t] + b_v[256 + t] + b_v[512 + t] + b_v[768 + t];

    const float4* p4 = (const float4*)(ws + WS_P) + (size_t)b * L * 256 + t;
    float acc = 0.f;
#pragma unroll 8
    for (int sk = 0; sk < L; ++sk) {
        float4 p = p4[(size_t)sk * 256];  // 16B coalesced, folds 4 K-chunks
        acc += E_s[h * L + sk] * (p.x + p.y + p.z + p.w);
    }

    out[(size_t)(b * L + sq) * EMBD + t] = (acc + sumE * bias) * (0.25f / sumE);
}

// ---------------------------------------------------------------------------
extern "C" void kernel_launch(void* const* d_in, const int* in_sizes, int n_in,
                              void* d_out, int out_size, void* d_ws, size_t ws_size,
                              hipStream_t stream) {
    const float* feat  = (const float*)d_in[0];  // (2,1,6,256,10,10)
    const float* query = (const float*)d_in[1];  // (2,100,256)
    const float4* Wv   = (const float4*)d_in[2]; // (1536,1024)
    const float* bv    = (const float*)d_in[3];  // (1024,)
    float* outp = (float*)d_out;                 // (2,100,256)
    float* ws   = (float*)d_ws;

    // K1: W-fold + E-compute (independent halves, one launch)
    prep_kernel<<<784, 256, 0, stream>>>(feat, query, Wv, ws);
    // K2: split-K GEMM partials (M=200,N=256,K=1536; 4 chunks, float4-packed)
    gemm_kernel<<<200, 256, 0, stream>>>(feat, ws, ws);
    // K3: E-weighted reduce + bias + normalize
    out_kernel<<<200, 256, 0, stream>>>(ws, bv, outp);
}

// Round 5
// 94.934 us; speedup vs baseline: 3.2696x; 1.2190x over previous
//
#include <hip/hip_runtime.h>

// Problem constants (from reference)
#define N_CAM   6
#define N_HEADS 8
#define EMBD    256
#define HS      32
#define L       100     // seq_len = 10*10
#define BS      2
#define CAM_STRIDE (L * EMBD)   // 25600 floats per (b, cam)
#define CK      (N_CAM * L)     // 600 combined (cam, sk) index

// Workspace layout (floats):
//   wsum : 1536*256 = 393216   folded W (sum over 4 ref slots)
//   ktr  : 2*8*32*600 = 307200 [b][h][d][cam*100+sk] transposed K
//   P    : 200*256*4 = 204800  split-K partials, float4 per (row,e): .c = chunk
//   E    : 200*8*100 = 160000  E[b*100+sq][h][sk] (camera-folded exp scores)
#define WS_WSUM 0
#define WS_KTR  (WS_WSUM + 1536 * 256)
#define WS_P    (WS_KTR + 2 * N_HEADS * HS * CK)
#define WS_E    (WS_P + 200 * 256 * 4)

// ---------------------------------------------------------------------------
// L1 (480 blocks) — independent prep jobs (R2-measured structure):
//  blocks [0,96):  transpose feat -> ktr[b][h][d][cam*100+sk]
//  blocks [96,480): fold W_v (1536x1024) over 4 ref slots -> wsum (1536x256)
// ---------------------------------------------------------------------------
__global__ __launch_bounds__(256) void prep_kernel(const float* __restrict__ feat,
                                                   const float4* __restrict__ Wv4,
                                                   float* __restrict__ ws) {
    const int t = threadIdx.x;
    if (blockIdx.x < 96) {
        __shared__ float tile[100 * 33];  // +1 pad: conflict-free column reads
        int blk = blockIdx.x;
        int b   = blk / 48;
        int rem = blk - b * 48;
        int cam = rem >> 3;
        int h   = rem & 7;
        const float* src = feat + (size_t)(b * N_CAM + cam) * CAM_STRIDE + h * HS;
        for (int idx = t; idx < 100 * 32; idx += 256) {
            int sk = idx >> 5;
            int d  = idx & 31;
            tile[sk * 33 + d] = src[sk * EMBD + d];       // 128B-contiguous runs
        }
        __syncthreads();
        float* ktr = ws + WS_KTR;
        for (int idx = t; idx < 100 * 32; idx += 256) {
            int d  = idx / 100;
            int sk = idx - d * 100;
            // lanes at fixed d write consecutive sk -> coalesced
            ktr[((size_t)(b * N_HEADS + h) * HS + d) * CK + cam * L + sk] = tile[sk * 33 + d];
        }
    } else {
        // wsum[i][e] = sum_ref W_v[i][ref*256+e]; 384*256 threads = 1536x64 f4
        int tid = (blockIdx.x - 96) * 256 + t;
        int i  = tid >> 6;
        int e4 = tid & 63;
        const float4* row = Wv4 + (size_t)i * 256;
        float4 a = row[e4];
        float4 b = row[64 + e4];
        float4 c = row[128 + e4];
        float4 d = row[192 + e4];
        float4 o;
        o.x = a.x + b.x + c.x + d.x;
        o.y = a.y + b.y + c.y + d.y;
        o.z = a.z + b.z + c.z + d.z;
        o.w = a.w + b.w + c.w + d.w;
        ((float4*)(ws + WS_WSUM))[(size_t)i * 64 + e4] = o;
    }
}

// ---------------------------------------------------------------------------
// L2 (800 blocks) — GEMM partials + E-compute, co-scheduled for TLP:
//  blocks [0,400):  split-K GEMM. block=(rg,c): rows rg*2..+2, K-chunk c of
//                   384 (4 chunks cover K=1536). P packed float4 per (row,e).
//  blocks [400,800): E[b,sq,h,sk] = sum_cam exp(q.k/sqrt(32)) from ktr,
//                   barrier-free coalesced reads (R2-measured structure).
// ---------------------------------------------------------------------------
__global__ __launch_bounds__(256) void mid_kernel(const float* __restrict__ feat,
                                                  const float* __restrict__ query,
                                                  const float* __restrict__ ws_r,
                                                  float* __restrict__ ws_w) {
    const int t = threadIdx.x;
    if (blockIdx.x < 400) {
        // ---- GEMM branch ----
        __shared__ float a_tile[2 * 384];
        const int rg = blockIdx.x >> 2;
        const int c  = blockIdx.x & 3;
        const int r0 = rg * 2;
        const int k0 = c * 384;

        // stage A: a_tile[j*384+kk] = v_in[r0+j][k0+kk]
        for (int i = t; i < 768; i += 256) {
            int j  = i >= 384;
            int kk = i - j * 384;
            int k  = k0 + kk;
            int cam = k >> 8, e2 = k & 255;
            int row = r0 + j;
            int b = row >= 100;
            int s = row - b * 100;
            a_tile[i] = feat[(size_t)(b * N_CAM + cam) * CAM_STRIDE + s * EMBD + e2];
        }
        __syncthreads();

        float acc0 = 0.f, acc1 = 0.f;
        const float* wp = ws_r + WS_WSUM + (size_t)k0 * 256 + t;
#pragma unroll 16
        for (int kk = 0; kk < 384; ++kk) {
            float w = wp[(size_t)kk * 256];   // coalesced across t
            acc0 += a_tile[kk] * w;           // LDS broadcast (free)
            acc1 += a_tile[384 + kk] * w;
        }

        float* P = ws_w + WS_P;
        P[((size_t)(r0 + 0) * 256 + t) * 4 + c] = acc0;
        P[((size_t)(r0 + 1) * 256 + t) * 4 + c] = acc1;
    } else {
        // ---- E branch: block = (b, h, sq-tile of 4) ----
        __shared__ float q_s[4 * 32];
        __shared__ float es[4 * CK];      // exp(scores) 4 sq x 600 ck
        int idx = blockIdx.x - 400;       // [0,400)
        int b   = idx / 200;
        int rem = idx - b * 200;
        int h   = rem / 25;
        int sqt = rem - h * 25;
        int sq0 = sqt * 4;

        if (t < 128)
            q_s[t] = query[(size_t)(b * L + sq0 + (t >> 5)) * EMBD + h * HS + (t & 31)];
        __syncthreads();

        const float scale = 0.17677669529663687f;  // 1/sqrt(32)
        const float* kt = ws_r + WS_KTR + (size_t)(b * N_HEADS + h) * HS * CK;

#pragma unroll
        for (int i = 0; i < 3; ++i) {
            int ck = t + i * 256;
            if (ck < CK) {
                float acc0 = 0.f, acc1 = 0.f, acc2 = 0.f, acc3 = 0.f;
#pragma unroll 8
                for (int d = 0; d < 32; ++d) {
                    float k = kt[(size_t)d * CK + ck];   // coalesced across lanes
                    acc0 += q_s[0 * 32 + d] * k;
                    acc1 += q_s[1 * 32 + d] * k;
                    acc2 += q_s[2 * 32 + d] * k;
                    acc3 += q_s[3 * 32 + d] * k;
                }
                es[0 * CK + ck] = __expf(acc0 * scale);
                es[1 * CK + ck] = __expf(acc1 * scale);
                es[2 * CK + ck] = __expf(acc2 * scale);
                es[3 * CK + ck] = __expf(acc3 * scale);
            }
        }
        __syncthreads();

        // camera fold -> E
        float* E = ws_w + WS_E;
        for (int p = t; p < 4 * L; p += 256) {
            int sj = p / 100, sk = p - sj * 100;
            float e = 0.f;
#pragma unroll
            for (int cam = 0; cam < N_CAM; ++cam)
                e += es[sj * CK + cam * L + sk];
            E[((size_t)(b * L + sq0 + sj) * N_HEADS + h) * L + sk] = e;
        }
    }
}

// ---------------------------------------------------------------------------
// L3 (200 blocks): block = (b, sq).
// out[b,sq,e] = (sum_sk E*(p.x+p.y+p.z+p.w) + sumE*bias_e) * 0.25/sumE
// (one float4 load folds all 4 K-chunks; bias folded via sumE)
// ---------------------------------------------------------------------------
__global__ __launch_bounds__(256) void out_kernel(const float* __restrict__ ws,
                                                  const float* __restrict__ b_v,
                                                  float* __restrict__ out) {
    __shared__ float E_s[N_HEADS * L];    // 800 floats
    const int t  = threadIdx.x;
    const int b  = blockIdx.x / 100;
    const int sq = blockIdx.x - b * 100;

    const float* E = ws + WS_E + (size_t)(b * L + sq) * N_HEADS * L;
    for (int i = t; i < N_HEADS * L; i += 256) E_s[i] = E[i];
    __syncthreads();

    const int h = t >> 5;
    float sumE = 0.f;
#pragma unroll 4
    for (int sk = 0; sk < L; ++sk) sumE += E_s[h * L + sk];   // broadcast reads

    float bias = b_v[t] + b_v[256 + t] + b_v[512 + t] + b_v[768 + t];

    const float4* p4 = (const float4*)(ws + WS_P) + (size_t)b * L * 256 + t;
    float acc = 0.f;
#pragma unroll 8
    for (int sk = 0; sk < L; ++sk) {
        float4 p = p4[(size_t)sk * 256];  // 16B coalesced, folds 4 K-chunks
        acc += E_s[h * L + sk] * (p.x + p.y + p.z + p.w);
    }

    out[(size_t)(b * L + sq) * EMBD + t] = (acc + sumE * bias) * (0.25f / sumE);
}

// ---------------------------------------------------------------------------
extern "C" void kernel_launch(void* const* d_in, const int* in_sizes, int n_in,
                              void* d_out, int out_size, void* d_ws, size_t ws_size,
                              hipStream_t stream) {
    const float* feat  = (const float*)d_in[0];  // (2,1,6,256,10,10)
    const float* query = (const float*)d_in[1];  // (2,100,256)
    const float4* Wv   = (const float4*)d_in[2]; // (1536,1024)
    const float* bv    = (const float*)d_in[3];  // (1024,)
    float* outp = (float*)d_out;                 // (2,100,256)
    float* ws   = (float*)d_ws;

    // L1: ktr transpose + W fold (independent, one launch)
    prep_kernel<<<480, 256, 0, stream>>>(feat, Wv, ws);
    // L2: split-K GEMM partials (400 blk) + E-compute (400 blk), co-scheduled
    mid_kernel<<<800, 256, 0, stream>>>(feat, query, ws, ws);
    // L3: E-weighted reduce + bias + normalize
    out_kernel<<<200, 256, 0, stream>>>(ws, bv, outp);
}